// Round 10
// baseline (1155.957 us; speedup 1.0000x reference)
//
#include <hip/hip_runtime.h>
#include <hip/hip_cooperative_groups.h>

// GCN: 4x GCNConv(128->128, sym norm, self-loops) + FC(128->32) + global mean pool.
// R9->R10: R9's mega-kernel returned all-zero output (absmax=454=max|ref|) -> the
// cooperative launch itself almost certainly failed (unchecked return; grid=768 likely
// > runtime's co-residency limit). Hedge: GRID 512 @ launch_bounds(256,2) (2 blk/CU,
// generous margins) AND check the launch result -- on failure, run the R7-verified
// 15-dispatch fallback in the same call. Phase bodies shared between both paths.

namespace cg = cooperative_groups;

#define N_NODES 50000
#define N_EDGES 600000
#define D 128
#define D_OUT 32
#define N_GRAPHS 64
#define N_SCAN_BLOCKS 49        // ceil(50000/1024)
#define SCAN_B 1024
#define GEMM_BLOCKS 782         // ceil(50000/64)
#define GRID 512
#define AGG_VB 12500            // 50000/4

typedef short short8 __attribute__((ext_vector_type(8)));
typedef float floatx4 __attribute__((ext_vector_type(4)));

__device__ inline unsigned bf16rne(float a) {
    unsigned u = __float_as_uint(a);
    return (u + 0x7fffu + ((u >> 16) & 1u)) >> 16;
}
__device__ inline unsigned bf16pair(float a, float b) {
    return bf16rne(a) | (bf16rne(b) << 16);
}
__device__ inline void fma8(float* acc, uint4 r, float w) {
    const unsigned hm = 0xffff0000u;
    acc[0] += w * __uint_as_float(r.x << 16);
    acc[1] += w * __uint_as_float(r.x & hm);
    acc[2] += w * __uint_as_float(r.y << 16);
    acc[3] += w * __uint_as_float(r.y & hm);
    acc[4] += w * __uint_as_float(r.z << 16);
    acc[5] += w * __uint_as_float(r.z & hm);
    acc[6] += w * __uint_as_float(r.w << 16);
    acc[7] += w * __uint_as_float(r.w & hm);
}

// ---------------- shared phase bodies (param: start block b, stride) ----------------

__device__ inline void gemm128_phase(const unsigned short* Ab, const unsigned short* WT,
                                     uint4* outb, unsigned short* smem, int b, int stride,
                                     int t) {
    int wave = t >> 6, lane = t & 63;
    int lm = lane & 15, lg = lane >> 4;
    for (int blk = b; blk < GEMM_BLOCKS; blk += stride) {
        int row0 = blk * 64 + wave * 16;
        int arow = row0 + lm;
        if (arow >= N_NODES) arow = N_NODES - 1;
        const short8* Arow = (const short8*)(Ab + (size_t)arow * 128);
        short8 a[4];
#pragma unroll
        for (int kc = 0; kc < 4; ++kc) a[kc] = Arow[kc * 4 + lg];
        floatx4 acc[8];
#pragma unroll
        for (int i = 0; i < 8; ++i) acc[i] = (floatx4){0.f, 0.f, 0.f, 0.f};
#pragma unroll
        for (int nt = 0; nt < 8; ++nt) {
            const short8* Brow = (const short8*)(WT + (size_t)(nt * 16 + lm) * 128);
#pragma unroll
            for (int kc = 0; kc < 4; ++kc)
                acc[nt] = __builtin_amdgcn_mfma_f32_16x16x32_bf16(a[kc], Brow[kc * 4 + lg],
                                                                  acc[nt], 0, 0, 0);
        }
        unsigned short* T = smem + wave * 16 * 136;
#pragma unroll
        for (int nt = 0; nt < 8; ++nt)
#pragma unroll
            for (int r = 0; r < 4; ++r)
                T[(lg * 4 + r) * 136 + nt * 16 + lm] = (unsigned short)bf16rne(acc[nt][r]);
        __syncthreads();
        int rr = lane >> 2, cseg = lane & 3;
        int orow = row0 + rr;
#pragma unroll
        for (int it = 0; it < 4; ++it) {
            uint4 v = *(const uint4*)&T[rr * 136 + cseg * 8 + it * 32];
            if (orow < N_NODES) outb[(size_t)orow * 16 + it * 4 + cseg] = v;
        }
        __syncthreads();
    }
}

__device__ inline void gemm128_f32_phase(const float* A, const unsigned short* WT,
                                         uint4* outb, unsigned short* smem, int b,
                                         int stride, int t) {
    int wave = t >> 6, lane = t & 63;
    int lm = lane & 15, lg = lane >> 4;
    for (int blk = b; blk < GEMM_BLOCKS; blk += stride) {
        int row0 = blk * 64 + wave * 16;
        int arow = row0 + lm;
        if (arow >= N_NODES) arow = N_NODES - 1;
        const float4* Arow = (const float4*)(A + (size_t)arow * 128);
        short8 a[4];
#pragma unroll
        for (int kc = 0; kc < 4; ++kc) {
            float4 f0 = Arow[kc * 8 + lg * 2];
            float4 f1 = Arow[kc * 8 + lg * 2 + 1];
            union { short8 s; uint4 u; } cvt;
            cvt.u = make_uint4(bf16pair(f0.x, f0.y), bf16pair(f0.z, f0.w),
                               bf16pair(f1.x, f1.y), bf16pair(f1.z, f1.w));
            a[kc] = cvt.s;
        }
        floatx4 acc[8];
#pragma unroll
        for (int i = 0; i < 8; ++i) acc[i] = (floatx4){0.f, 0.f, 0.f, 0.f};
#pragma unroll
        for (int nt = 0; nt < 8; ++nt) {
            const short8* Brow = (const short8*)(WT + (size_t)(nt * 16 + lm) * 128);
#pragma unroll
            for (int kc = 0; kc < 4; ++kc)
                acc[nt] = __builtin_amdgcn_mfma_f32_16x16x32_bf16(a[kc], Brow[kc * 4 + lg],
                                                                  acc[nt], 0, 0, 0);
        }
        unsigned short* T = smem + wave * 16 * 136;
#pragma unroll
        for (int nt = 0; nt < 8; ++nt)
#pragma unroll
            for (int r = 0; r < 4; ++r)
                T[(lg * 4 + r) * 136 + nt * 16 + lm] = (unsigned short)bf16rne(acc[nt][r]);
        __syncthreads();
        int rr = lane >> 2, cseg = lane & 3;
        int orow = row0 + rr;
#pragma unroll
        for (int it = 0; it < 4; ++it) {
            uint4 v = *(const uint4*)&T[rr * 136 + cseg * 8 + it * 32];
            if (orow < N_NODES) outb[(size_t)orow * 16 + it * 4 + cseg] = v;
        }
        __syncthreads();
    }
}

__device__ inline void gemm32_phase(const unsigned short* Ab, const unsigned short* WcT,
                                    uint4* outb, unsigned short* smem, int b, int stride,
                                    int t) {
    int wave = t >> 6, lane = t & 63;
    int lm = lane & 15, lg = lane >> 4;
    for (int blk = b; blk < GEMM_BLOCKS; blk += stride) {
        int row0 = blk * 64 + wave * 16;
        int arow = row0 + lm;
        if (arow >= N_NODES) arow = N_NODES - 1;
        const short8* Arow = (const short8*)(Ab + (size_t)arow * 128);
        short8 a[4];
#pragma unroll
        for (int kc = 0; kc < 4; ++kc) a[kc] = Arow[kc * 4 + lg];
        floatx4 acc[2];
#pragma unroll
        for (int i = 0; i < 2; ++i) acc[i] = (floatx4){0.f, 0.f, 0.f, 0.f};
#pragma unroll
        for (int nt = 0; nt < 2; ++nt) {
            const short8* Brow = (const short8*)(WcT + (size_t)(nt * 16 + lm) * 128);
#pragma unroll
            for (int kc = 0; kc < 4; ++kc)
                acc[nt] = __builtin_amdgcn_mfma_f32_16x16x32_bf16(a[kc], Brow[kc * 4 + lg],
                                                                  acc[nt], 0, 0, 0);
        }
        unsigned short* T = smem + wave * 16 * 32;
#pragma unroll
        for (int nt = 0; nt < 2; ++nt)
#pragma unroll
            for (int r = 0; r < 4; ++r)
                T[(lg * 4 + r) * 32 + nt * 16 + lm] = (unsigned short)bf16rne(acc[nt][r]);
        __syncthreads();
        int rr = lane >> 2, cseg = lane & 3;
        int orow = row0 + rr;
        uint4 v = *(const uint4*)&T[rr * 32 + cseg * 8];
        if (orow < N_NODES) outb[(size_t)orow * 4 + cseg] = v;
        __syncthreads();
    }
}

__device__ inline void agg128_phase(const unsigned* hWb, const float* bias,
                                    const float* dinv, const int* row_off,
                                    const int* indeg, const int2* csr, uint4* outb,
                                    int b, int stride, int t) {
    int wave = t >> 6, lane = t & 63;
    int q = lane >> 4, c = lane & 15;
    const uint4* hW4 = (const uint4*)hWb;
    for (int vb = b; vb < AGG_VB; vb += stride) {
        int n = vb * 4 + wave;
        float acc[8] = {0.f, 0.f, 0.f, 0.f, 0.f, 0.f, 0.f, 0.f};
        int beg = row_off[n];
        int end = beg + indeg[n];
        int e = beg + q;
        while (e + 4 < end) {
            int2 e0 = csr[e];
            int2 e1 = csr[e + 4];
            uint4 r0 = hW4[e0.x * 16 + c];
            uint4 r1 = hW4[e1.x * 16 + c];
            fma8(acc, r0, __int_as_float(e0.y));
            fma8(acc, r1, __int_as_float(e1.y));
            e += 8;
        }
        if (e < end) {
            int2 e0 = csr[e];
            uint4 r0 = hW4[e0.x * 16 + c];
            fma8(acc, r0, __int_as_float(e0.y));
        }
#pragma unroll
        for (int i = 0; i < 8; ++i) {
            acc[i] += __shfl_xor(acc[i], 16, 64);
            acc[i] += __shfl_xor(acc[i], 32, 64);
        }
        if (q == 0) {
            float di = dinv[n];
            float sw = di * di;
            uint4 hv = hW4[n * 16 + c];
            fma8(acc, hv, sw);
            float4 bA = ((const float4*)bias)[c * 2];
            float4 bB = ((const float4*)bias)[c * 2 + 1];
            uint4 pk;
            pk.x = bf16pair(acc[0] + bA.x, acc[1] + bA.y);
            pk.y = bf16pair(acc[2] + bA.z, acc[3] + bA.w);
            pk.z = bf16pair(acc[4] + bB.x, acc[5] + bB.y);
            pk.w = bf16pair(acc[6] + bB.z, acc[7] + bB.w);
            outb[(size_t)n * 16 + c] = pk;
        }
    }
}

__device__ inline void agg32_phase(const unsigned* Gb, const float* dinv,
                                   const int* row_off, const int* indeg,
                                   const int2* csr, float* p, int b, int stride, int t) {
    int wave = t >> 6, lane = t & 63;
    int q = lane >> 4, c = lane & 15;
    const unsigned hm = 0xffff0000u;
    for (int vb = b; vb < AGG_VB; vb += stride) {
        int n = vb * 4 + wave;
        float a0 = 0.f, a1 = 0.f;
        int beg = row_off[n];
        int end = beg + indeg[n];
        int e = beg + q;
        while (e + 4 < end) {
            int2 e0 = csr[e];
            int2 e1 = csr[e + 4];
            unsigned r0 = Gb[e0.x * 16 + c];
            unsigned r1 = Gb[e1.x * 16 + c];
            float w0 = __int_as_float(e0.y), w1 = __int_as_float(e1.y);
            a0 += w0 * __uint_as_float(r0 << 16) + w1 * __uint_as_float(r1 << 16);
            a1 += w0 * __uint_as_float(r0 & hm) + w1 * __uint_as_float(r1 & hm);
            e += 8;
        }
        if (e < end) {
            int2 e0 = csr[e];
            unsigned r0 = Gb[e0.x * 16 + c];
            float w0 = __int_as_float(e0.y);
            a0 += w0 * __uint_as_float(r0 << 16);
            a1 += w0 * __uint_as_float(r0 & hm);
        }
        a0 += __shfl_xor(a0, 16, 64); a0 += __shfl_xor(a0, 32, 64);
        a1 += __shfl_xor(a1, 16, 64); a1 += __shfl_xor(a1, 32, 64);
        if (q == 0) {
            float di = dinv[n];
            float sw = di * di;
            unsigned sv = Gb[n * 16 + c];
            a0 += sw * __uint_as_float(sv << 16);
            a1 += sw * __uint_as_float(sv & hm);
            ((float2*)p)[n * 16 + c] = make_float2(a0, a1);
        }
    }
}

__device__ inline void prep_block(int b, int t, char* smem_raw,
                                  const float* W1, const float* W2, const float* W3,
                                  const float* W4, const float* fcW, const float* fcb,
                                  const float* b4,
                                  unsigned* WT1, unsigned* WT2, unsigned* WT3,
                                  unsigned short* WcT, float* bc) {
    if (b < 3) {
        const float* W = (b == 0) ? W1 : (b == 1) ? W2 : W3;
        unsigned* WT = (b == 0) ? WT1 : (b == 1) ? WT2 : WT3;
        int n = t >> 1, hf = t & 1;
        uint4* WT4 = (uint4*)WT;
        for (int i = 0; i < 8; ++i) {
            int k0 = hf * 64 + i * 8;
            uint4 pk;
            pk.x = bf16pair(W[(k0 + 0) * 128 + n], W[(k0 + 1) * 128 + n]);
            pk.y = bf16pair(W[(k0 + 2) * 128 + n], W[(k0 + 3) * 128 + n]);
            pk.z = bf16pair(W[(k0 + 4) * 128 + n], W[(k0 + 5) * 128 + n]);
            pk.w = bf16pair(W[(k0 + 6) * 128 + n], W[(k0 + 7) * 128 + n]);
            WT4[n * 16 + hf * 8 + i] = pk;
        }
    } else if (b < 19) {
        float* F = (float*)smem_raw;  // fcW stage, 16KB
        for (int i = 0; i < 16; ++i) F[i * 256 + t] = fcW[i * 256 + t];
        __syncthreads();
        int c = t & 31, il = t >> 5;
        int i = (b - 3) * 8 + il;
        float acc = 0.f;
        for (int k = 0; k < 128; ++k) acc += W4[i * 128 + k] * F[k * 32 + c];
        WcT[c * 128 + i] = (unsigned short)bf16rne(acc);
        __syncthreads();
    } else if (b == 19) {
        if (t < 32) {
            float acc = fcb[t];
            for (int k = 0; k < 128; ++k) acc += b4[k] * fcW[k * 32 + t];
            bc[t] = acc;
        }
    }
}

__device__ inline void scanC_block(int b, int t, char* smem_raw,
                                   const int* indeg, int* bsum) {
    int* sdata = (int*)smem_raw;
    int i0 = b * SCAN_B + t * 4;
    int v0 = (i0 + 0 < N_NODES) ? indeg[i0 + 0] : 0;
    int v1 = (i0 + 1 < N_NODES) ? indeg[i0 + 1] : 0;
    int v2 = (i0 + 2 < N_NODES) ? indeg[i0 + 2] : 0;
    int v3 = (i0 + 3 < N_NODES) ? indeg[i0 + 3] : 0;
    sdata[t] = v0 + v1 + v2 + v3;
    __syncthreads();
    for (int s = 128; s > 0; s >>= 1) {
        if (t < s) sdata[t] += sdata[t + s];
        __syncthreads();
    }
    if (t == 0) bsum[b] = sdata[0];
}

__device__ inline void scanD_block(int b, int t, char* smem_raw, const int* indeg,
                                   const int* bsum, int* row_off, float* dinv) {
    int* sdata = (int*)smem_raw;  // [0..255] sums, [256] boff
    int i0 = b * SCAN_B + t * 4;
    int v0 = (i0 + 0 < N_NODES) ? indeg[i0 + 0] : 0;
    int v1 = (i0 + 1 < N_NODES) ? indeg[i0 + 1] : 0;
    int v2 = (i0 + 2 < N_NODES) ? indeg[i0 + 2] : 0;
    int v3 = (i0 + 3 < N_NODES) ? indeg[i0 + 3] : 0;
    int tsum = v0 + v1 + v2 + v3;
    if (t < 64) {
        int v = (t < b) ? bsum[t] : 0;
#pragma unroll
        for (int off = 1; off < 64; off <<= 1) v += __shfl_xor(v, off, 64);
        if (t == 0) sdata[256] = v;
    }
    sdata[t] = tsum;
    __syncthreads();
    for (int off = 1; off < 256; off <<= 1) {
        int add = (t >= off) ? sdata[t - off] : 0;
        __syncthreads();
        sdata[t] += add;
        __syncthreads();
    }
    int base = sdata[256] + sdata[t] - tsum;
    if (i0 + 0 < N_NODES) { row_off[i0 + 0] = base;                  dinv[i0 + 0] = rsqrtf((float)(v0 + 1)); }
    if (i0 + 1 < N_NODES) { row_off[i0 + 1] = base + v0;             dinv[i0 + 1] = rsqrtf((float)(v1 + 1)); }
    if (i0 + 2 < N_NODES) { row_off[i0 + 2] = base + v0 + v1;        dinv[i0 + 2] = rsqrtf((float)(v2 + 1)); }
    if (i0 + 3 < N_NODES) { row_off[i0 + 3] = base + v0 + v1 + v2;   dinv[i0 + 3] = rsqrtf((float)(v3 + 1)); }
}

__device__ inline void tail_block(int gg, int t, char* smem_raw, const float* p,
                                  const int* batch, const float* bc, float* out) {
    float* partial = (float*)smem_raw;  // [8][32]
    int rg = t >> 5, d = t & 31;
    int lo = 0, hi = N_NODES;
    while (lo < hi) { int m = (lo + hi) >> 1; if (batch[m] < gg) lo = m + 1; else hi = m; }
    int lo2 = lo, hi2 = N_NODES;
    while (lo2 < hi2) { int m = (lo2 + hi2) >> 1; if (batch[m] < gg + 1) lo2 = m + 1; else hi2 = m; }
    int cnt = lo2 - lo;
    float acc = 0.f;
    int n = lo + rg;
    for (; n + 24 < lo2; n += 32) {
        float u0 = p[n * 32 + d];
        float u1 = p[(n + 8) * 32 + d];
        float u2 = p[(n + 16) * 32 + d];
        float u3 = p[(n + 24) * 32 + d];
        acc += (u0 + u1) + (u2 + u3);
    }
    for (; n < lo2; n += 8) acc += p[n * 32 + d];
    partial[rg * 32 + d] = acc;
    __syncthreads();
    if (rg == 0) {
        float s = 0.f;
#pragma unroll
        for (int r = 0; r < 8; ++r) s += partial[r * 32 + d];
        out[gg * 32 + d] = (cnt > 0) ? s / (float)cnt + bc[d] : 0.f;
    }
}

// ---------------- params ----------------

struct MegaParams {
    const float* x;
    const int* src;
    const int* dst;
    const int* batch;
    const float *W1, *b1, *W2, *b2, *W3, *b3, *W4, *b4, *fcW, *fcb;
    float* out;
    unsigned* hWb;
    unsigned* hb;
    int2* csr;
    int* row_off;
    int* indeg;
    int* cursor;
    float* dinv;
    int* bsum;
    unsigned *WT1, *WT2, *WT3;
    unsigned short* WcT;
    float* bc;
    float* p;
};

// ---------------- cooperative mega kernel ----------------

__global__ __launch_bounds__(256, 2) void mega_kernel(MegaParams P) {
    cg::grid_group g = cg::this_grid();
    __shared__ __align__(16) char smem_raw[17408];
    unsigned short* smem_us = (unsigned short*)smem_raw;
    const int b = blockIdx.x;
    const int t = threadIdx.x;

    // Phase A: prep (blocks 0..19) + zero indeg/cursor (blocks 20..)
    if (b < 20) {
        prep_block(b, t, smem_raw, P.W1, P.W2, P.W3, P.W4, P.fcW, P.fcb, P.b4,
                   P.WT1, P.WT2, P.WT3, P.WcT, P.bc);
    } else {
        int idx = (b - 20) * 256 + t;  // (512-20)*256 = 125952 >= 50000
        if (idx < N_NODES) { P.indeg[idx] = 0; P.cursor[idx] = 0; }
    }
    g.sync();

    // Phase B: hist + gemm1 (independent)
    for (int e = b * 256 + t; e < N_EDGES; e += GRID * 256)
        atomicAdd(&P.indeg[P.dst[e]], 1);
    gemm128_f32_phase(P.x, (const unsigned short*)P.WT1, (uint4*)P.hWb, smem_us, b, GRID, t);
    g.sync();

    if (b < N_SCAN_BLOCKS) scanC_block(b, t, smem_raw, P.indeg, P.bsum);
    g.sync();
    if (b < N_SCAN_BLOCKS) scanD_block(b, t, smem_raw, P.indeg, P.bsum, P.row_off, P.dinv);
    g.sync();

    for (int e = b * 256 + t; e < N_EDGES; e += GRID * 256) {
        int d = P.dst[e], s = P.src[e];
        int pos = atomicAdd(&P.cursor[d], 1);
        P.csr[P.row_off[d] + pos] = make_int2(s, __float_as_int(P.dinv[s] * P.dinv[d]));
    }
    g.sync();

    agg128_phase(P.hWb, P.b1, P.dinv, P.row_off, P.indeg, P.csr, (uint4*)P.hb, b, GRID, t);
    g.sync();
    gemm128_phase((const unsigned short*)P.hb, (const unsigned short*)P.WT2,
                  (uint4*)P.hWb, smem_us, b, GRID, t);
    g.sync();
    agg128_phase(P.hWb, P.b2, P.dinv, P.row_off, P.indeg, P.csr, (uint4*)P.hb, b, GRID, t);
    g.sync();
    gemm128_phase((const unsigned short*)P.hb, (const unsigned short*)P.WT3,
                  (uint4*)P.hWb, smem_us, b, GRID, t);
    g.sync();
    agg128_phase(P.hWb, P.b3, P.dinv, P.row_off, P.indeg, P.csr, (uint4*)P.hb, b, GRID, t);
    g.sync();
    gemm32_phase((const unsigned short*)P.hb, P.WcT, (uint4*)P.hWb, smem_us, b, GRID, t);
    g.sync();
    agg32_phase(P.hWb, P.dinv, P.row_off, P.indeg, P.csr, P.p, b, GRID, t);
    g.sync();

    if (b < N_GRAPHS) tail_block(b, t, smem_raw, P.p, P.batch, P.bc, P.out);
}

// ---------------- standalone fallback kernels (R7 path) ----------------

__global__ void hist_kernel(const int* __restrict__ dst, int* __restrict__ indeg) {
    int e = blockIdx.x * blockDim.x + threadIdx.x;
    if (e < N_EDGES) atomicAdd(&indeg[dst[e]], 1);
}
__global__ void scanC_k(const int* indeg, int* bsum) {
    __shared__ __align__(16) char smem[1056];
    scanC_block(blockIdx.x, threadIdx.x, smem, indeg, bsum);
}
__global__ void scanD_k(const int* indeg, const int* bsum, int* row_off, float* dinv) {
    __shared__ __align__(16) char smem[1056];
    scanD_block(blockIdx.x, threadIdx.x, smem, indeg, bsum, row_off, dinv);
}
__global__ void fill_k(const int* __restrict__ src, const int* __restrict__ dst,
                       const int* __restrict__ row_off, int* __restrict__ cursor,
                       const float* __restrict__ dinv, int2* __restrict__ csr) {
    int e = blockIdx.x * blockDim.x + threadIdx.x;
    if (e >= N_EDGES) return;
    int d = dst[e], s = src[e];
    int pos = atomicAdd(&cursor[d], 1);
    csr[row_off[d] + pos] = make_int2(s, __float_as_int(dinv[s] * dinv[d]));
}
__global__ __launch_bounds__(256) void prep_k(const float* W1, const float* W2,
                                              const float* W3, const float* W4,
                                              const float* fcW, const float* fcb,
                                              const float* b4, unsigned* WT1,
                                              unsigned* WT2, unsigned* WT3,
                                              unsigned short* WcT, float* bc) {
    __shared__ __align__(16) char smem[16384];
    prep_block(blockIdx.x, threadIdx.x, smem, W1, W2, W3, W4, fcW, fcb, b4,
               WT1, WT2, WT3, WcT, bc);
}
__global__ __launch_bounds__(256) void gemm1_k(const float* A, const unsigned short* WT,
                                               uint4* outb) {
    __shared__ __align__(16) unsigned short smem[4 * 16 * 136];
    gemm128_f32_phase(A, WT, outb, smem, blockIdx.x, gridDim.x, threadIdx.x);
}
__global__ __launch_bounds__(256) void gemm_k(const unsigned short* Ab,
                                              const unsigned short* WT, uint4* outb) {
    __shared__ __align__(16) unsigned short smem[4 * 16 * 136];
    gemm128_phase(Ab, WT, outb, smem, blockIdx.x, gridDim.x, threadIdx.x);
}
__global__ __launch_bounds__(256) void gemm32_k(const unsigned short* Ab,
                                                const unsigned short* WcT, uint4* outb) {
    __shared__ __align__(16) unsigned short smem[4 * 16 * 32];
    gemm32_phase(Ab, WcT, outb, smem, blockIdx.x, gridDim.x, threadIdx.x);
}
__global__ __launch_bounds__(256) void agg_k(const unsigned* hWb, const float* bias,
                                             const float* dinv, const int* row_off,
                                             const int* indeg, const int2* csr,
                                             uint4* outb) {
    agg128_phase(hWb, bias, dinv, row_off, indeg, csr, outb, blockIdx.x, gridDim.x,
                 threadIdx.x);
}
__global__ __launch_bounds__(256) void agg32_k(const unsigned* Gb, const float* dinv,
                                               const int* row_off, const int* indeg,
                                               const int2* csr, float* p) {
    agg32_phase(Gb, dinv, row_off, indeg, csr, p, blockIdx.x, gridDim.x, threadIdx.x);
}
__global__ __launch_bounds__(256) void tail_k(const float* p, const int* batch,
                                              const float* bc, float* out) {
    __shared__ __align__(16) char smem[1024];
    tail_block(blockIdx.x, threadIdx.x, smem, p, batch, bc, out);
}

// ---------------- launch ----------------

static inline size_t align_up(size_t x) { return (x + 255) & ~(size_t)255; }

extern "C" void kernel_launch(void* const* d_in, const int* in_sizes, int n_in,
                              void* d_out, int out_size, void* d_ws, size_t ws_size,
                              hipStream_t stream) {
    const float* x = (const float*)d_in[0];
    const int* edge_index = (const int*)d_in[1];
    const int* batch = (const int*)d_in[2];

    char* base = (char*)d_ws;
    size_t o = 0;
    unsigned* hWb = (unsigned*)(base + o);  o = align_up(o + (size_t)N_NODES * D * 2);
    unsigned* hb = (unsigned*)(base + o);   o = align_up(o + (size_t)N_NODES * D * 2);
    int2* csr = (int2*)(base + o);          o = align_up(o + (size_t)N_EDGES * 8);
    int* row_off = (int*)(base + o);        o = align_up(o + (size_t)N_NODES * 4);
    int* indeg = (int*)(base + o);          o = align_up(o + (size_t)2 * N_NODES * 4);
    int* cursor = indeg + N_NODES;          // contiguous with indeg (single memset)
    float* dinv = (float*)(base + o);       o = align_up(o + (size_t)N_NODES * 4);
    int* bsum = (int*)(base + o);           o = align_up(o + 256);
    unsigned* WT1 = (unsigned*)(base + o);  o = align_up(o + (size_t)D * D * 2);
    unsigned* WT2 = (unsigned*)(base + o);  o = align_up(o + (size_t)D * D * 2);
    unsigned* WT3 = (unsigned*)(base + o);  o = align_up(o + (size_t)D * D * 2);
    unsigned short* WcT = (unsigned short*)(base + o); o = align_up(o + (size_t)D * D_OUT * 2);
    float* bc = (float*)(base + o);         o = align_up(o + (size_t)D_OUT * 4);
    float* p = (float*)(base + o);          o = align_up(o + (size_t)N_NODES * D_OUT * 4);

    MegaParams P;
    P.x = x;
    P.src = edge_index;
    P.dst = edge_index + N_EDGES;
    P.batch = batch;
    P.W1 = (const float*)d_in[3];  P.b1 = (const float*)d_in[4];
    P.W2 = (const float*)d_in[5];  P.b2 = (const float*)d_in[6];
    P.W3 = (const float*)d_in[7];  P.b3 = (const float*)d_in[8];
    P.W4 = (const float*)d_in[9];  P.b4 = (const float*)d_in[10];
    P.fcW = (const float*)d_in[11]; P.fcb = (const float*)d_in[12];
    P.out = (float*)d_out;
    P.hWb = hWb; P.hb = hb; P.csr = csr; P.row_off = row_off;
    P.indeg = indeg; P.cursor = cursor; P.dinv = dinv; P.bsum = bsum;
    P.WT1 = WT1; P.WT2 = WT2; P.WT3 = WT3; P.WcT = WcT; P.bc = bc; P.p = p;

    void* args[] = {(void*)&P};
    hipError_t cerr = hipLaunchCooperativeKernel((const void*)mega_kernel, dim3(GRID),
                                                 dim3(256), args, 0, stream);
    if (cerr != hipSuccess) {
        (void)hipGetLastError();  // clear sticky error; run the R7-verified path
        hipMemsetAsync(indeg, 0, (size_t)2 * N_NODES * 4, stream);
        hist_kernel<<<(N_EDGES + 255) / 256, 256, 0, stream>>>(P.dst, indeg);
        scanC_k<<<N_SCAN_BLOCKS, 256, 0, stream>>>(indeg, bsum);
        scanD_k<<<N_SCAN_BLOCKS, 256, 0, stream>>>(indeg, bsum, row_off, dinv);
        fill_k<<<(N_EDGES + 255) / 256, 256, 0, stream>>>(P.src, P.dst, row_off, cursor,
                                                          dinv, csr);
        prep_k<<<20, 256, 0, stream>>>(P.W1, P.W2, P.W3, P.W4, P.fcW, P.fcb, P.b4,
                                       WT1, WT2, WT3, WcT, bc);
        gemm1_k<<<GEMM_BLOCKS, 256, 0, stream>>>(x, (const unsigned short*)WT1,
                                                 (uint4*)hWb);
        agg_k<<<AGG_VB, 256, 0, stream>>>(hWb, P.b1, dinv, row_off, indeg, csr,
                                          (uint4*)hb);
        gemm_k<<<GEMM_BLOCKS, 256, 0, stream>>>((const unsigned short*)hb,
                                                (const unsigned short*)WT2, (uint4*)hWb);
        agg_k<<<AGG_VB, 256, 0, stream>>>(hWb, P.b2, dinv, row_off, indeg, csr,
                                          (uint4*)hb);
        gemm_k<<<GEMM_BLOCKS, 256, 0, stream>>>((const unsigned short*)hb,
                                                (const unsigned short*)WT3, (uint4*)hWb);
        agg_k<<<AGG_VB, 256, 0, stream>>>(hWb, P.b3, dinv, row_off, indeg, csr,
                                          (uint4*)hb);
        gemm32_k<<<GEMM_BLOCKS, 256, 0, stream>>>((const unsigned short*)hb, WcT,
                                                  (uint4*)hWb);
        agg32_k<<<AGG_VB, 256, 0, stream>>>(hWb, dinv, row_off, indeg, csr, p);
        tail_k<<<N_GRAPHS, 256, 0, stream>>>(p, batch, bc, (float*)d_out);
    }
}

// Round 11
// 376.135 us; speedup vs baseline: 3.0733x; 3.0733x over previous
//
#include <hip/hip_runtime.h>

// GCN: 4x GCNConv(128->128, sym norm, self-loops) + FC(128->32) + global mean pool.
// R10->R11: cooperative mega-kernel abandoned (grid.sync ~40-50us each on 8-XCD MI355X;
// 1065us vs 355us dispatch path). Instead: agg->gemm fused PER LAYER with no global
// barrier needed (gemm A-rows are node-local to the agg outputs of the same block).
// Kills 3 dispatches + 77MB of h write/re-read traffic. scanC+prep merged; cursor
// zeroed inside scanD. 15 -> 11 dispatches. LDS A-tile stride 17 uint4 (2-way bank
// aliasing = free per m136); epilogue transpose tile aliases the A-tile.

#define N_NODES 50000
#define N_EDGES 600000
#define D 128
#define D_OUT 32
#define N_GRAPHS 64
#define SCAN_B 1024
#define N_SCAN_BLOCKS 49          // ceil(50000/1024)
#define GEMM_BLOCKS 782           // ceil(50000/64)
#define AGG_GRID 12500            // 50000/4

typedef short short8 __attribute__((ext_vector_type(8)));
typedef float floatx4 __attribute__((ext_vector_type(4)));

__device__ inline unsigned bf16rne(float a) {
    unsigned u = __float_as_uint(a);
    return (u + 0x7fffu + ((u >> 16) & 1u)) >> 16;
}
__device__ inline unsigned bf16pair(float a, float b) {
    return bf16rne(a) | (bf16rne(b) << 16);
}
__device__ inline void fma8(float* acc, uint4 r, float w) {
    const unsigned hm = 0xffff0000u;
    acc[0] += w * __uint_as_float(r.x << 16);
    acc[1] += w * __uint_as_float(r.x & hm);
    acc[2] += w * __uint_as_float(r.y << 16);
    acc[3] += w * __uint_as_float(r.y & hm);
    acc[4] += w * __uint_as_float(r.z << 16);
    acc[5] += w * __uint_as_float(r.z & hm);
    acc[6] += w * __uint_as_float(r.w << 16);
    acc[7] += w * __uint_as_float(r.w & hm);
}

// ---------------- graph preprocessing ----------------

__global__ void hist_kernel(const int* __restrict__ dst, int* __restrict__ indeg) {
    int e = blockIdx.x * blockDim.x + threadIdx.x;
    if (e < N_EDGES) atomicAdd(&indeg[dst[e]], 1);
}

// blocks 0..48: per-chunk degree sums. blocks 49..68: weight prep (WT1-3, WcT, bc).
__global__ __launch_bounds__(256) void scanC_prep_kernel(
        const int* __restrict__ indeg, int* __restrict__ bsum,
        const float* __restrict__ W1, const float* __restrict__ W2,
        const float* __restrict__ W3, const float* __restrict__ W4,
        const float* __restrict__ fcW, const float* __restrict__ fcb,
        const float* __restrict__ b4,
        unsigned* __restrict__ WT1, unsigned* __restrict__ WT2,
        unsigned* __restrict__ WT3, unsigned short* __restrict__ WcT,
        float* __restrict__ bc) {
    __shared__ __align__(16) char smem_raw[16384];
    int blk = blockIdx.x, t = threadIdx.x;
    if (blk < N_SCAN_BLOCKS) {
        int* sdata = (int*)smem_raw;
        int i0 = blk * SCAN_B + t * 4;
        int v0 = (i0 + 0 < N_NODES) ? indeg[i0 + 0] : 0;
        int v1 = (i0 + 1 < N_NODES) ? indeg[i0 + 1] : 0;
        int v2 = (i0 + 2 < N_NODES) ? indeg[i0 + 2] : 0;
        int v3 = (i0 + 3 < N_NODES) ? indeg[i0 + 3] : 0;
        sdata[t] = v0 + v1 + v2 + v3;
        __syncthreads();
        for (int s = 128; s > 0; s >>= 1) {
            if (t < s) sdata[t] += sdata[t + s];
            __syncthreads();
        }
        if (t == 0) bsum[blk] = sdata[0];
        return;
    }
    int b = blk - N_SCAN_BLOCKS;  // 0..19
    if (b < 3) {
        const float* W = (b == 0) ? W1 : (b == 1) ? W2 : W3;
        unsigned* WT = (b == 0) ? WT1 : (b == 1) ? WT2 : WT3;
        int n = t >> 1, hf = t & 1;
        uint4* WT4 = (uint4*)WT;
        for (int i = 0; i < 8; ++i) {
            int k0 = hf * 64 + i * 8;
            uint4 pk;
            pk.x = bf16pair(W[(k0 + 0) * 128 + n], W[(k0 + 1) * 128 + n]);
            pk.y = bf16pair(W[(k0 + 2) * 128 + n], W[(k0 + 3) * 128 + n]);
            pk.z = bf16pair(W[(k0 + 4) * 128 + n], W[(k0 + 5) * 128 + n]);
            pk.w = bf16pair(W[(k0 + 6) * 128 + n], W[(k0 + 7) * 128 + n]);
            WT4[n * 16 + hf * 8 + i] = pk;
        }
    } else if (b < 19) {
        float* F = (float*)smem_raw;  // fcW [128][32]
        for (int i = 0; i < 16; ++i) F[i * 256 + t] = fcW[i * 256 + t];
        __syncthreads();
        int c = t & 31, il = t >> 5;
        int i = (b - 3) * 8 + il;  // k index
        float acc = 0.f;
        for (int k = 0; k < 128; ++k) acc += W4[i * 128 + k] * F[k * 32 + c];
        WcT[c * 128 + i] = (unsigned short)bf16rne(acc);
    } else {
        if (t < 32) {
            float acc = fcb[t];
            for (int k = 0; k < 128; ++k) acc += b4[k] * fcW[k * 32 + t];
            bc[t] = acc;
        }
    }
}

// exclusive scan -> row_off + dinv + cursor zero.
__global__ void scanD_kernel(const int* __restrict__ indeg, const int* __restrict__ bsum,
                             int* __restrict__ row_off, float* __restrict__ dinv,
                             int* __restrict__ cursor) {
    __shared__ int sdata[257];
    int blk = blockIdx.x, t = threadIdx.x;
    int i0 = blk * SCAN_B + t * 4;
    int v0 = (i0 + 0 < N_NODES) ? indeg[i0 + 0] : 0;
    int v1 = (i0 + 1 < N_NODES) ? indeg[i0 + 1] : 0;
    int v2 = (i0 + 2 < N_NODES) ? indeg[i0 + 2] : 0;
    int v3 = (i0 + 3 < N_NODES) ? indeg[i0 + 3] : 0;
    int tsum = v0 + v1 + v2 + v3;
    if (t < 64) {
        int v = (t < blk) ? bsum[t] : 0;
#pragma unroll
        for (int off = 1; off < 64; off <<= 1) v += __shfl_xor(v, off, 64);
        if (t == 0) sdata[256] = v;
    }
    sdata[t] = tsum;
    __syncthreads();
    for (int off = 1; off < 256; off <<= 1) {
        int add = (t >= off) ? sdata[t - off] : 0;
        __syncthreads();
        sdata[t] += add;
        __syncthreads();
    }
    int base = sdata[256] + sdata[t] - tsum;
    if (i0 + 0 < N_NODES) { row_off[i0 + 0] = base;                dinv[i0 + 0] = rsqrtf((float)(v0 + 1)); cursor[i0 + 0] = 0; }
    if (i0 + 1 < N_NODES) { row_off[i0 + 1] = base + v0;           dinv[i0 + 1] = rsqrtf((float)(v1 + 1)); cursor[i0 + 1] = 0; }
    if (i0 + 2 < N_NODES) { row_off[i0 + 2] = base + v0 + v1;      dinv[i0 + 2] = rsqrtf((float)(v2 + 1)); cursor[i0 + 2] = 0; }
    if (i0 + 3 < N_NODES) { row_off[i0 + 3] = base + v0 + v1 + v2; dinv[i0 + 3] = rsqrtf((float)(v3 + 1)); cursor[i0 + 3] = 0; }
}

__global__ void fill_kernel(const int* __restrict__ src, const int* __restrict__ dst,
                            const int* __restrict__ row_off, int* __restrict__ cursor,
                            const float* __restrict__ dinv, int2* __restrict__ csr) {
    int e = blockIdx.x * blockDim.x + threadIdx.x;
    if (e >= N_EDGES) return;
    int d = dst[e], s = src[e];
    int pos = atomicAdd(&cursor[d], 1);
    csr[row_off[d] + pos] = make_int2(s, __float_as_int(dinv[s] * dinv[d]));
}

// ---------------- layer 1 GEMM (x fp32 -> bf16 hW) ----------------

__global__ __launch_bounds__(256) void gemm1_kernel(const float* __restrict__ A,
                                                    const unsigned short* __restrict__ WT,
                                                    uint4* __restrict__ outb) {
    __shared__ unsigned short tile[4][16 * 136];
    int t = threadIdx.x;
    int wave = t >> 6, lane = t & 63;
    int row0 = blockIdx.x * 64 + wave * 16;
    int lm = lane & 15, lg = lane >> 4;

    int arow = row0 + lm;
    if (arow >= N_NODES) arow = N_NODES - 1;
    const float4* Arow = (const float4*)(A + (size_t)arow * 128);
    short8 a[4];
#pragma unroll
    for (int kc = 0; kc < 4; ++kc) {
        float4 f0 = Arow[kc * 8 + lg * 2];
        float4 f1 = Arow[kc * 8 + lg * 2 + 1];
        union { short8 s; uint4 u; } cvt;
        cvt.u = make_uint4(bf16pair(f0.x, f0.y), bf16pair(f0.z, f0.w),
                           bf16pair(f1.x, f1.y), bf16pair(f1.z, f1.w));
        a[kc] = cvt.s;
    }
    floatx4 acc[8];
#pragma unroll
    for (int i = 0; i < 8; ++i) acc[i] = (floatx4){0.f, 0.f, 0.f, 0.f};
#pragma unroll
    for (int nt = 0; nt < 8; ++nt) {
        const short8* Brow = (const short8*)(WT + (size_t)(nt * 16 + lm) * 128);
#pragma unroll
        for (int kc = 0; kc < 4; ++kc)
            acc[nt] = __builtin_amdgcn_mfma_f32_16x16x32_bf16(a[kc], Brow[kc * 4 + lg],
                                                              acc[nt], 0, 0, 0);
    }
    unsigned short* T = tile[wave];
#pragma unroll
    for (int nt = 0; nt < 8; ++nt)
#pragma unroll
        for (int r = 0; r < 4; ++r)
            T[(lg * 4 + r) * 136 + nt * 16 + lm] = (unsigned short)bf16rne(acc[nt][r]);
    __syncthreads();
    int rr = lane >> 2, cseg = lane & 3;
    int orow = row0 + rr;
#pragma unroll
    for (int it = 0; it < 4; ++it) {
        uint4 v = *(const uint4*)&T[rr * 136 + cseg * 8 + it * 32];
        if (orow < N_NODES) outb[(size_t)orow * 16 + it * 4 + cseg] = v;
    }
}

// ---------------- fused agg + GEMM layers ----------------

// Per wave: agg 16 nodes (gather bf16 rows from srcHW, quarter-wave/edge), +bias,
// pack h rows into LDS A-tile (stride 17 uint4 -> 2-way bank alias, free), then
// MFMA h @ WT -> next hW (bf16). No h through global.
__global__ __launch_bounds__(256) void fused_layer_kernel(
        const unsigned* __restrict__ srcHW, const float* __restrict__ bias,
        const float* __restrict__ dinv, const int* __restrict__ row_off,
        const int* __restrict__ indeg, const int2* __restrict__ csr,
        const unsigned short* __restrict__ WT, uint4* __restrict__ outb) {
    __shared__ __align__(16) uint4 At[4][16][17];  // 17408 B
    int t = threadIdx.x;
    int wave = t >> 6, lane = t & 63;
    int q = lane >> 4, c = lane & 15;
    int row0 = blockIdx.x * 64 + wave * 16;
    const uint4* hW4 = (const uint4*)srcHW;

    // ---- agg stage: 16 nodes per wave ----
    for (int i = 0; i < 16; ++i) {
        int n = row0 + i;
        if (n >= N_NODES) n = N_NODES - 1;
        float acc[8] = {0.f, 0.f, 0.f, 0.f, 0.f, 0.f, 0.f, 0.f};
        int beg = row_off[n];
        int end = beg + indeg[n];
        int e = beg + q;
        while (e + 4 < end) {
            int2 e0 = csr[e];
            int2 e1 = csr[e + 4];
            uint4 r0 = hW4[e0.x * 16 + c];
            uint4 r1 = hW4[e1.x * 16 + c];
            fma8(acc, r0, __int_as_float(e0.y));
            fma8(acc, r1, __int_as_float(e1.y));
            e += 8;
        }
        if (e < end) {
            int2 e0 = csr[e];
            uint4 r0 = hW4[e0.x * 16 + c];
            fma8(acc, r0, __int_as_float(e0.y));
        }
#pragma unroll
        for (int j = 0; j < 8; ++j) {
            acc[j] += __shfl_xor(acc[j], 16, 64);
            acc[j] += __shfl_xor(acc[j], 32, 64);
        }
        if (q == 0) {
            float di = dinv[n];
            float sw = di * di;
            uint4 hv = hW4[n * 16 + c];
            fma8(acc, hv, sw);
            float4 bA = ((const float4*)bias)[c * 2];
            float4 bB = ((const float4*)bias)[c * 2 + 1];
            uint4 pk;
            pk.x = bf16pair(acc[0] + bA.x, acc[1] + bA.y);
            pk.y = bf16pair(acc[2] + bA.z, acc[3] + bA.w);
            pk.z = bf16pair(acc[4] + bB.x, acc[5] + bB.y);
            pk.w = bf16pair(acc[6] + bB.z, acc[7] + bB.w);
            At[wave][i][c] = pk;
        }
    }
    __syncthreads();  // cross-lane LDS visibility (wave-internal, but uniform & cheap)

    // ---- GEMM stage: A-frags from LDS, B from WT (L1-resident) ----
    int lm = lane & 15, lg = lane >> 4;
    short8 a[4];
#pragma unroll
    for (int kc = 0; kc < 4; ++kc)
        a[kc] = *(const short8*)&At[wave][lm][kc * 4 + lg];
    floatx4 acc2[8];
#pragma unroll
    for (int i = 0; i < 8; ++i) acc2[i] = (floatx4){0.f, 0.f, 0.f, 0.f};
#pragma unroll
    for (int nt = 0; nt < 8; ++nt) {
        const short8* Brow = (const short8*)(WT + (size_t)(nt * 16 + lm) * 128);
#pragma unroll
        for (int kc = 0; kc < 4; ++kc)
            acc2[nt] = __builtin_amdgcn_mfma_f32_16x16x32_bf16(a[kc], Brow[kc * 4 + lg],
                                                               acc2[nt], 0, 0, 0);
    }
    // epilogue: D-layout -> row-major; transpose tile aliases A-tile (A is in regs now)
    unsigned short* T = (unsigned short*)&At[wave][0][0];  // 16x136 shorts = 4352 B
#pragma unroll
    for (int nt = 0; nt < 8; ++nt)
#pragma unroll
        for (int r = 0; r < 4; ++r)
            T[(lg * 4 + r) * 136 + nt * 16 + lm] = (unsigned short)bf16rne(acc2[nt][r]);
    __syncthreads();
    int rr = lane >> 2, cseg = lane & 3;
    int orow = row0 + rr;
#pragma unroll
    for (int it = 0; it < 4; ++it) {
        uint4 v = *(const uint4*)&T[rr * 136 + cseg * 8 + it * 32];
        if (orow < N_NODES) outb[(size_t)orow * 16 + it * 4 + cseg] = v;
    }
}

// Layer-4 variant: agg(+b3) then MFMA with WcT (32 cols) -> Gb bf16 [N][32].
__global__ __launch_bounds__(256) void fused_layer32_kernel(
        const unsigned* __restrict__ srcHW, const float* __restrict__ bias,
        const float* __restrict__ dinv, const int* __restrict__ row_off,
        const int* __restrict__ indeg, const int2* __restrict__ csr,
        const unsigned short* __restrict__ WcT, uint4* __restrict__ outb) {
    __shared__ __align__(16) uint4 At[4][16][17];
    int t = threadIdx.x;
    int wave = t >> 6, lane = t & 63;
    int q = lane >> 4, c = lane & 15;
    int row0 = blockIdx.x * 64 + wave * 16;
    const uint4* hW4 = (const uint4*)srcHW;

    for (int i = 0; i < 16; ++i) {
        int n = row0 + i;
        if (n >= N_NODES) n = N_NODES - 1;
        float acc[8] = {0.f, 0.f, 0.f, 0.f, 0.f, 0.f, 0.f, 0.f};
        int beg = row_off[n];
        int end = beg + indeg[n];
        int e = beg + q;
        while (e + 4 < end) {
            int2 e0 = csr[e];
            int2 e1 = csr[e + 4];
            uint4 r0 = hW4[e0.x * 16 + c];
            uint4 r1 = hW4[e1.x * 16 + c];
            fma8(acc, r0, __int_as_float(e0.y));
            fma8(acc, r1, __int_as_float(e1.y));
            e += 8;
        }
        if (e < end) {
            int2 e0 = csr[e];
            uint4 r0 = hW4[e0.x * 16 + c];
            fma8(acc, r0, __int_as_float(e0.y));
        }
#pragma unroll
        for (int j = 0; j < 8; ++j) {
            acc[j] += __shfl_xor(acc[j], 16, 64);
            acc[j] += __shfl_xor(acc[j], 32, 64);
        }
        if (q == 0) {
            float di = dinv[n];
            float sw = di * di;
            uint4 hv = hW4[n * 16 + c];
            fma8(acc, hv, sw);
            float4 bA = ((const float4*)bias)[c * 2];
            float4 bB = ((const float4*)bias)[c * 2 + 1];
            uint4 pk;
            pk.x = bf16pair(acc[0] + bA.x, acc[1] + bA.y);
            pk.y = bf16pair(acc[2] + bA.z, acc[3] + bA.w);
            pk.z = bf16pair(acc[4] + bB.x, acc[5] + bB.y);
            pk.w = bf16pair(acc[6] + bB.z, acc[7] + bB.w);
            At[wave][i][c] = pk;
        }
    }
    __syncthreads();

    int lm = lane & 15, lg = lane >> 4;
    short8 a[4];
#pragma unroll
    for (int kc = 0; kc < 4; ++kc)
        a[kc] = *(const short8*)&At[wave][lm][kc * 4 + lg];
    floatx4 acc2[2];
#pragma unroll
    for (int i = 0; i < 2; ++i) acc2[i] = (floatx4){0.f, 0.f, 0.f, 0.f};
#pragma unroll
    for (int nt = 0; nt < 2; ++nt) {
        const short8* Brow = (const short8*)(WcT + (size_t)(nt * 16 + lm) * 128);
#pragma unroll
        for (int kc = 0; kc < 4; ++kc)
            acc2[nt] = __builtin_amdgcn_mfma_f32_16x16x32_bf16(a[kc], Brow[kc * 4 + lg],
                                                               acc2[nt], 0, 0, 0);
    }
    unsigned short* T = (unsigned short*)&At[wave][0][0];  // 16x32 shorts
#pragma unroll
    for (int nt = 0; nt < 2; ++nt)
#pragma unroll
        for (int r = 0; r < 4; ++r)
            T[(lg * 4 + r) * 32 + nt * 16 + lm] = (unsigned short)bf16rne(acc2[nt][r]);
    __syncthreads();
    int rr = lane >> 2, cseg = lane & 3;
    int orow = row0 + rr;
    uint4 v = *(const uint4*)&T[rr * 32 + cseg * 8];
    if (orow < N_NODES) outb[(size_t)orow * 4 + cseg] = v;
}

// ---------------- 32-dim agg + tail ----------------

__global__ __launch_bounds__(256) void agg32_kernel(const unsigned* __restrict__ Gb,
                                                    const float* __restrict__ dinv,
                                                    const int* __restrict__ row_off,
                                                    const int* __restrict__ indeg,
                                                    const int2* __restrict__ csr,
                                                    float* __restrict__ p) {
    int wave = threadIdx.x >> 6;
    int lane = threadIdx.x & 63;
    int n = blockIdx.x * 4 + wave;
    if (n >= N_NODES) return;
    int q = lane >> 4;
    int c = lane & 15;
    const unsigned hm = 0xffff0000u;
    float a0 = 0.f, a1 = 0.f;
    int beg = row_off[n];
    int end = beg + indeg[n];
    int e = beg + q;
    while (e + 4 < end) {
        int2 e0 = csr[e];
        int2 e1 = csr[e + 4];
        unsigned r0 = Gb[e0.x * 16 + c];
        unsigned r1 = Gb[e1.x * 16 + c];
        float w0 = __int_as_float(e0.y), w1 = __int_as_float(e1.y);
        a0 += w0 * __uint_as_float(r0 << 16) + w1 * __uint_as_float(r1 << 16);
        a1 += w0 * __uint_as_float(r0 & hm) + w1 * __uint_as_float(r1 & hm);
        e += 8;
    }
    if (e < end) {
        int2 e0 = csr[e];
        unsigned r0 = Gb[e0.x * 16 + c];
        float w0 = __int_as_float(e0.y);
        a0 += w0 * __uint_as_float(r0 << 16);
        a1 += w0 * __uint_as_float(r0 & hm);
    }
    a0 += __shfl_xor(a0, 16, 64); a0 += __shfl_xor(a0, 32, 64);
    a1 += __shfl_xor(a1, 16, 64); a1 += __shfl_xor(a1, 32, 64);
    if (q == 0) {
        float di = dinv[n];
        float sw = di * di;
        unsigned sv = Gb[n * 16 + c];
        a0 += sw * __uint_as_float(sv << 16);
        a1 += sw * __uint_as_float(sv & hm);
        ((float2*)p)[n * 16 + c] = make_float2(a0, a1);
    }
}

__global__ __launch_bounds__(256) void tail_kernel(const float* __restrict__ p,
                                                   const int* __restrict__ batch,
                                                   const float* __restrict__ bc,
                                                   float* __restrict__ out) {
    __shared__ float partial[8][32];
    int g = blockIdx.x;
    int t = threadIdx.x;
    int rg = t >> 5, d = t & 31;
    int lo = 0, hi = N_NODES;
    while (lo < hi) { int m = (lo + hi) >> 1; if (batch[m] < g) lo = m + 1; else hi = m; }
    int lo2 = lo, hi2 = N_NODES;
    while (lo2 < hi2) { int m = (lo2 + hi2) >> 1; if (batch[m] < g + 1) lo2 = m + 1; else hi2 = m; }
    int cnt = lo2 - lo;
    float acc = 0.f;
    int n = lo + rg;
    for (; n + 24 < lo2; n += 32) {
        float u0 = p[n * 32 + d];
        float u1 = p[(n + 8) * 32 + d];
        float u2 = p[(n + 16) * 32 + d];
        float u3 = p[(n + 24) * 32 + d];
        acc += (u0 + u1) + (u2 + u3);
    }
    for (; n < lo2; n += 8) acc += p[n * 32 + d];
    partial[rg][d] = acc;
    __syncthreads();
    if (rg == 0) {
        float s = 0.f;
#pragma unroll
        for (int r = 0; r < 8; ++r) s += partial[r][d];
        out[g * 32 + d] = (cnt > 0) ? s / (float)cnt + bc[d] : 0.f;
    }
}

// ---------------- launch ----------------

static inline size_t align_up(size_t x) { return (x + 255) & ~(size_t)255; }

extern "C" void kernel_launch(void* const* d_in, const int* in_sizes, int n_in,
                              void* d_out, int out_size, void* d_ws, size_t ws_size,
                              hipStream_t stream) {
    const float* x = (const float*)d_in[0];
    const int* edge_index = (const int*)d_in[1];
    const int* batch = (const int*)d_in[2];
    const float* W1 = (const float*)d_in[3];
    const float* b1 = (const float*)d_in[4];
    const float* W2 = (const float*)d_in[5];
    const float* b2 = (const float*)d_in[6];
    const float* W3 = (const float*)d_in[7];
    const float* b3 = (const float*)d_in[8];
    const float* W4 = (const float*)d_in[9];
    const float* b4 = (const float*)d_in[10];
    const float* fcW = (const float*)d_in[11];
    const float* fcb = (const float*)d_in[12];
    float* out = (float*)d_out;

    const int* src = edge_index;
    const int* dst = edge_index + N_EDGES;

    char* base = (char*)d_ws;
    size_t o = 0;
    unsigned* buf0 = (unsigned*)(base + o); o = align_up(o + (size_t)N_NODES * D * 2);
    unsigned* buf1 = (unsigned*)(base + o); o = align_up(o + (size_t)N_NODES * D * 2);
    int2* csr = (int2*)(base + o);          o = align_up(o + (size_t)N_EDGES * 8);
    int* row_off = (int*)(base + o);        o = align_up(o + (size_t)N_NODES * 4);
    int* indeg = (int*)(base + o);          o = align_up(o + (size_t)N_NODES * 4);
    int* cursor = (int*)(base + o);         o = align_up(o + (size_t)N_NODES * 4);
    float* dinv = (float*)(base + o);       o = align_up(o + (size_t)N_NODES * 4);
    int* bsum = (int*)(base + o);           o = align_up(o + 256);
    unsigned* WT1 = (unsigned*)(base + o);  o = align_up(o + (size_t)D * D * 2);
    unsigned* WT2 = (unsigned*)(base + o);  o = align_up(o + (size_t)D * D * 2);
    unsigned* WT3 = (unsigned*)(base + o);  o = align_up(o + (size_t)D * D * 2);
    unsigned short* WcT = (unsigned short*)(base + o); o = align_up(o + (size_t)D * D_OUT * 2);
    float* bc = (float*)(base + o);         o = align_up(o + (size_t)D_OUT * 4);
    float* p = (float*)(base + o);          o = align_up(o + (size_t)N_NODES * D_OUT * 4);

    // 1. zero indeg (cursor zeroed in scanD)
    hipMemsetAsync(indeg, 0, (size_t)N_NODES * 4, stream);
    // 2. degree histogram
    hist_kernel<<<(N_EDGES + 255) / 256, 256, 0, stream>>>(dst, indeg);
    // 3. chunk sums + weight prep (independent, merged)
    scanC_prep_kernel<<<N_SCAN_BLOCKS + 20, 256, 0, stream>>>(
        indeg, bsum, W1, W2, W3, W4, fcW, fcb, b4, WT1, WT2, WT3, WcT, bc);
    // 4. scan -> row_off, dinv (+ cursor zero)
    scanD_kernel<<<N_SCAN_BLOCKS, 256, 0, stream>>>(indeg, bsum, row_off, dinv, cursor);
    // 5. CSR fill
    fill_kernel<<<(N_EDGES + 255) / 256, 256, 0, stream>>>(src, dst, row_off, cursor,
                                                           dinv, csr);
    // 6. layer-1 GEMM: x @ W1 -> buf0 (bf16)
    gemm1_kernel<<<GEMM_BLOCKS, 256, 0, stream>>>(x, (const unsigned short*)WT1,
                                                  (uint4*)buf0);
    // 7-9. fused agg+GEMM layers
    fused_layer_kernel<<<GEMM_BLOCKS, 256, 0, stream>>>(
        buf0, b1, dinv, row_off, indeg, csr, (const unsigned short*)WT2, (uint4*)buf1);
    fused_layer_kernel<<<GEMM_BLOCKS, 256, 0, stream>>>(
        buf1, b2, dinv, row_off, indeg, csr, (const unsigned short*)WT3, (uint4*)buf0);
    fused_layer32_kernel<<<GEMM_BLOCKS, 256, 0, stream>>>(
        buf0, b3, dinv, row_off, indeg, csr, WcT, (uint4*)buf1);  // Gb = buf1
    // 10. final aggregation on 32-dim G
    agg32_kernel<<<AGG_GRID, 256, 0, stream>>>(buf1, dinv, row_off, indeg, csr, p);
    // 11. pool + bias
    tail_kernel<<<N_GRAPHS, 256, 0, stream>>>(p, batch, bc, out);
}

// Round 12
// 347.442 us; speedup vs baseline: 3.3270x; 1.0826x over previous
//
#include <hip/hip_runtime.h>

// GCN: 4x GCNConv(128->128, sym norm, self-loops) + FC(128->32) + global mean pool.
// R11->R12: layer fusion REVERTED (it capped agg at ~3 blocks/CU -> latency-bound agg
// lost 2.2x parallelism; 61us fused vs ~52us split). Back to split agg/gemm with R11's
// orthogonal merges (scanC+prep, cursor zero in scanD). New: agg gathers 4 edge-slots
// per quarter-wave per trip (16 gathers in flight/wave, one latency round covers
// deg<=16 = 90% of Poisson(12) nodes; invalid slots clamp index, weight=0).

#define N_NODES 50000
#define N_EDGES 600000
#define D 128
#define D_OUT 32
#define N_GRAPHS 64
#define SCAN_B 1024
#define N_SCAN_BLOCKS 49          // ceil(50000/1024)
#define GEMM_BLOCKS 782           // ceil(50000/64)
#define AGG_GRID 12500            // 50000/4

typedef short short8 __attribute__((ext_vector_type(8)));
typedef float floatx4 __attribute__((ext_vector_type(4)));

__device__ inline unsigned bf16rne(float a) {
    unsigned u = __float_as_uint(a);
    return (u + 0x7fffu + ((u >> 16) & 1u)) >> 16;
}
__device__ inline unsigned bf16pair(float a, float b) {
    return bf16rne(a) | (bf16rne(b) << 16);
}
__device__ inline void fma8(float* acc, uint4 r, float w) {
    const unsigned hm = 0xffff0000u;
    acc[0] += w * __uint_as_float(r.x << 16);
    acc[1] += w * __uint_as_float(r.x & hm);
    acc[2] += w * __uint_as_float(r.y << 16);
    acc[3] += w * __uint_as_float(r.y & hm);
    acc[4] += w * __uint_as_float(r.z << 16);
    acc[5] += w * __uint_as_float(r.z & hm);
    acc[6] += w * __uint_as_float(r.w << 16);
    acc[7] += w * __uint_as_float(r.w & hm);
}

// ---------------- graph preprocessing ----------------

__global__ void hist_kernel(const int* __restrict__ dst, int* __restrict__ indeg) {
    int e = blockIdx.x * blockDim.x + threadIdx.x;
    if (e < N_EDGES) atomicAdd(&indeg[dst[e]], 1);
}

// blocks 0..48: per-chunk degree sums. blocks 49..68: weight prep (WT1-3, WcT, bc).
__global__ __launch_bounds__(256) void scanC_prep_kernel(
        const int* __restrict__ indeg, int* __restrict__ bsum,
        const float* __restrict__ W1, const float* __restrict__ W2,
        const float* __restrict__ W3, const float* __restrict__ W4,
        const float* __restrict__ fcW, const float* __restrict__ fcb,
        const float* __restrict__ b4,
        unsigned* __restrict__ WT1, unsigned* __restrict__ WT2,
        unsigned* __restrict__ WT3, unsigned short* __restrict__ WcT,
        float* __restrict__ bc) {
    __shared__ __align__(16) char smem_raw[16384];
    int blk = blockIdx.x, t = threadIdx.x;
    if (blk < N_SCAN_BLOCKS) {
        int* sdata = (int*)smem_raw;
        int i0 = blk * SCAN_B + t * 4;
        int v0 = (i0 + 0 < N_NODES) ? indeg[i0 + 0] : 0;
        int v1 = (i0 + 1 < N_NODES) ? indeg[i0 + 1] : 0;
        int v2 = (i0 + 2 < N_NODES) ? indeg[i0 + 2] : 0;
        int v3 = (i0 + 3 < N_NODES) ? indeg[i0 + 3] : 0;
        sdata[t] = v0 + v1 + v2 + v3;
        __syncthreads();
        for (int s = 128; s > 0; s >>= 1) {
            if (t < s) sdata[t] += sdata[t + s];
            __syncthreads();
        }
        if (t == 0) bsum[blk] = sdata[0];
        return;
    }
    int b = blk - N_SCAN_BLOCKS;  // 0..19
    if (b < 3) {
        const float* W = (b == 0) ? W1 : (b == 1) ? W2 : W3;
        unsigned* WT = (b == 0) ? WT1 : (b == 1) ? WT2 : WT3;
        int n = t >> 1, hf = t & 1;
        uint4* WT4 = (uint4*)WT;
        for (int i = 0; i < 8; ++i) {
            int k0 = hf * 64 + i * 8;
            uint4 pk;
            pk.x = bf16pair(W[(k0 + 0) * 128 + n], W[(k0 + 1) * 128 + n]);
            pk.y = bf16pair(W[(k0 + 2) * 128 + n], W[(k0 + 3) * 128 + n]);
            pk.z = bf16pair(W[(k0 + 4) * 128 + n], W[(k0 + 5) * 128 + n]);
            pk.w = bf16pair(W[(k0 + 6) * 128 + n], W[(k0 + 7) * 128 + n]);
            WT4[n * 16 + hf * 8 + i] = pk;
        }
    } else if (b < 19) {
        float* F = (float*)smem_raw;  // fcW [128][32]
        for (int i = 0; i < 16; ++i) F[i * 256 + t] = fcW[i * 256 + t];
        __syncthreads();
        int c = t & 31, il = t >> 5;
        int i = (b - 3) * 8 + il;  // k index
        float acc = 0.f;
        for (int k = 0; k < 128; ++k) acc += W4[i * 128 + k] * F[k * 32 + c];
        WcT[c * 128 + i] = (unsigned short)bf16rne(acc);
    } else {
        if (t < 32) {
            float acc = fcb[t];
            for (int k = 0; k < 128; ++k) acc += b4[k] * fcW[k * 32 + t];
            bc[t] = acc;
        }
    }
}

// exclusive scan -> row_off + dinv + cursor zero.
__global__ void scanD_kernel(const int* __restrict__ indeg, const int* __restrict__ bsum,
                             int* __restrict__ row_off, float* __restrict__ dinv,
                             int* __restrict__ cursor) {
    __shared__ int sdata[257];
    int blk = blockIdx.x, t = threadIdx.x;
    int i0 = blk * SCAN_B + t * 4;
    int v0 = (i0 + 0 < N_NODES) ? indeg[i0 + 0] : 0;
    int v1 = (i0 + 1 < N_NODES) ? indeg[i0 + 1] : 0;
    int v2 = (i0 + 2 < N_NODES) ? indeg[i0 + 2] : 0;
    int v3 = (i0 + 3 < N_NODES) ? indeg[i0 + 3] : 0;
    int tsum = v0 + v1 + v2 + v3;
    if (t < 64) {
        int v = (t < blk) ? bsum[t] : 0;
#pragma unroll
        for (int off = 1; off < 64; off <<= 1) v += __shfl_xor(v, off, 64);
        if (t == 0) sdata[256] = v;
    }
    sdata[t] = tsum;
    __syncthreads();
    for (int off = 1; off < 256; off <<= 1) {
        int add = (t >= off) ? sdata[t - off] : 0;
        __syncthreads();
        sdata[t] += add;
        __syncthreads();
    }
    int base = sdata[256] + sdata[t] - tsum;
    if (i0 + 0 < N_NODES) { row_off[i0 + 0] = base;                dinv[i0 + 0] = rsqrtf((float)(v0 + 1)); cursor[i0 + 0] = 0; }
    if (i0 + 1 < N_NODES) { row_off[i0 + 1] = base + v0;           dinv[i0 + 1] = rsqrtf((float)(v1 + 1)); cursor[i0 + 1] = 0; }
    if (i0 + 2 < N_NODES) { row_off[i0 + 2] = base + v0 + v1;      dinv[i0 + 2] = rsqrtf((float)(v2 + 1)); cursor[i0 + 2] = 0; }
    if (i0 + 3 < N_NODES) { row_off[i0 + 3] = base + v0 + v1 + v2; dinv[i0 + 3] = rsqrtf((float)(v3 + 1)); cursor[i0 + 3] = 0; }
}

__global__ void fill_kernel(const int* __restrict__ src, const int* __restrict__ dst,
                            const int* __restrict__ row_off, int* __restrict__ cursor,
                            const float* __restrict__ dinv, int2* __restrict__ csr) {
    int e = blockIdx.x * blockDim.x + threadIdx.x;
    if (e >= N_EDGES) return;
    int d = dst[e], s = src[e];
    int pos = atomicAdd(&cursor[d], 1);
    csr[row_off[d] + pos] = make_int2(s, __float_as_int(dinv[s] * dinv[d]));
}

// ---------------- MFMA GEMMs (R7-verified) ----------------

__global__ __launch_bounds__(256) void gemm1_kernel(const float* __restrict__ A,
                                                    const unsigned short* __restrict__ WT,
                                                    uint4* __restrict__ outb) {
    __shared__ unsigned short tile[4][16 * 136];
    int t = threadIdx.x;
    int wave = t >> 6, lane = t & 63;
    int row0 = blockIdx.x * 64 + wave * 16;
    int lm = lane & 15, lg = lane >> 4;

    int arow = row0 + lm;
    if (arow >= N_NODES) arow = N_NODES - 1;
    const float4* Arow = (const float4*)(A + (size_t)arow * 128);
    short8 a[4];
#pragma unroll
    for (int kc = 0; kc < 4; ++kc) {
        float4 f0 = Arow[kc * 8 + lg * 2];
        float4 f1 = Arow[kc * 8 + lg * 2 + 1];
        union { short8 s; uint4 u; } cvt;
        cvt.u = make_uint4(bf16pair(f0.x, f0.y), bf16pair(f0.z, f0.w),
                           bf16pair(f1.x, f1.y), bf16pair(f1.z, f1.w));
        a[kc] = cvt.s;
    }
    floatx4 acc[8];
#pragma unroll
    for (int i = 0; i < 8; ++i) acc[i] = (floatx4){0.f, 0.f, 0.f, 0.f};
#pragma unroll
    for (int nt = 0; nt < 8; ++nt) {
        const short8* Brow = (const short8*)(WT + (size_t)(nt * 16 + lm) * 128);
#pragma unroll
        for (int kc = 0; kc < 4; ++kc)
            acc[nt] = __builtin_amdgcn_mfma_f32_16x16x32_bf16(a[kc], Brow[kc * 4 + lg],
                                                              acc[nt], 0, 0, 0);
    }
    unsigned short* T = tile[wave];
#pragma unroll
    for (int nt = 0; nt < 8; ++nt)
#pragma unroll
        for (int r = 0; r < 4; ++r)
            T[(lg * 4 + r) * 136 + nt * 16 + lm] = (unsigned short)bf16rne(acc[nt][r]);
    __syncthreads();
    int rr = lane >> 2, cseg = lane & 3;
    int orow = row0 + rr;
#pragma unroll
    for (int it = 0; it < 4; ++it) {
        uint4 v = *(const uint4*)&T[rr * 136 + cseg * 8 + it * 32];
        if (orow < N_NODES) outb[(size_t)orow * 16 + it * 4 + cseg] = v;
    }
}

__global__ __launch_bounds__(256) void gemm_kernel(const unsigned short* __restrict__ Ab,
                                                   const unsigned short* __restrict__ WT,
                                                   uint4* __restrict__ outb) {
    __shared__ unsigned short tile[4][16 * 136];
    int t = threadIdx.x;
    int wave = t >> 6, lane = t & 63;
    int row0 = blockIdx.x * 64 + wave * 16;
    int lm = lane & 15, lg = lane >> 4;

    int arow = row0 + lm;
    if (arow >= N_NODES) arow = N_NODES - 1;
    const short8* Arow = (const short8*)(Ab + (size_t)arow * 128);
    short8 a[4];
#pragma unroll
    for (int kc = 0; kc < 4; ++kc) a[kc] = Arow[kc * 4 + lg];
    floatx4 acc[8];
#pragma unroll
    for (int i = 0; i < 8; ++i) acc[i] = (floatx4){0.f, 0.f, 0.f, 0.f};
#pragma unroll
    for (int nt = 0; nt < 8; ++nt) {
        const short8* Brow = (const short8*)(WT + (size_t)(nt * 16 + lm) * 128);
#pragma unroll
        for (int kc = 0; kc < 4; ++kc)
            acc[nt] = __builtin_amdgcn_mfma_f32_16x16x32_bf16(a[kc], Brow[kc * 4 + lg],
                                                              acc[nt], 0, 0, 0);
    }
    unsigned short* T = tile[wave];
#pragma unroll
    for (int nt = 0; nt < 8; ++nt)
#pragma unroll
        for (int r = 0; r < 4; ++r)
            T[(lg * 4 + r) * 136 + nt * 16 + lm] = (unsigned short)bf16rne(acc[nt][r]);
    __syncthreads();
    int rr = lane >> 2, cseg = lane & 3;
    int orow = row0 + rr;
#pragma unroll
    for (int it = 0; it < 4; ++it) {
        uint4 v = *(const uint4*)&T[rr * 136 + cseg * 8 + it * 32];
        if (orow < N_NODES) outb[(size_t)orow * 16 + it * 4 + cseg] = v;
    }
}

__global__ __launch_bounds__(256) void gemm32_kernel(const unsigned short* __restrict__ Ab,
                                                     const unsigned short* __restrict__ WcT,
                                                     uint4* __restrict__ outb) {
    __shared__ unsigned short tile[4][16 * 32];
    int t = threadIdx.x;
    int wave = t >> 6, lane = t & 63;
    int row0 = blockIdx.x * 64 + wave * 16;
    int lm = lane & 15, lg = lane >> 4;

    int arow = row0 + lm;
    if (arow >= N_NODES) arow = N_NODES - 1;
    const short8* Arow = (const short8*)(Ab + (size_t)arow * 128);
    short8 a[4];
#pragma unroll
    for (int kc = 0; kc < 4; ++kc) a[kc] = Arow[kc * 4 + lg];
    floatx4 acc[2];
#pragma unroll
    for (int i = 0; i < 2; ++i) acc[i] = (floatx4){0.f, 0.f, 0.f, 0.f};
#pragma unroll
    for (int nt = 0; nt < 2; ++nt) {
        const short8* Brow = (const short8*)(WcT + (size_t)(nt * 16 + lm) * 128);
#pragma unroll
        for (int kc = 0; kc < 4; ++kc)
            acc[nt] = __builtin_amdgcn_mfma_f32_16x16x32_bf16(a[kc], Brow[kc * 4 + lg],
                                                              acc[nt], 0, 0, 0);
    }
    unsigned short* T = tile[wave];
#pragma unroll
    for (int nt = 0; nt < 2; ++nt)
#pragma unroll
        for (int r = 0; r < 4; ++r)
            T[(lg * 4 + r) * 32 + nt * 16 + lm] = (unsigned short)bf16rne(acc[nt][r]);
    __syncthreads();
    int rr = lane >> 2, cseg = lane & 3;
    int orow = row0 + rr;
    uint4 v = *(const uint4*)&T[rr * 32 + cseg * 8];
    if (orow < N_NODES) outb[(size_t)orow * 4 + cseg] = v;
}

// ---------------- aggregation: 4 edge-slots per quarter-wave per trip ----------------

// One wave/node; quarter-wave (16 lanes) x uint4 = bf16 row. Per trip each quarter
// issues 4 gathers (stride 16 covers deg<=16 in ONE latency round; invalid slots
// clamp to e (dup row, L1-hit) with weight 0 -- no divergence).
__global__ __launch_bounds__(256) void agg_kernel(const unsigned* __restrict__ hWb,
                                                  const float* __restrict__ bias,
                                                  const float* __restrict__ dinv,
                                                  const int* __restrict__ row_off,
                                                  const int* __restrict__ indeg,
                                                  const int2* __restrict__ csr,
                                                  uint4* __restrict__ outb) {
    int wave = threadIdx.x >> 6;
    int lane = threadIdx.x & 63;
    int n = blockIdx.x * 4 + wave;  // N_NODES % 4 == 0
    int q = lane >> 4;
    int c = lane & 15;
    const uint4* hW4 = (const uint4*)hWb;

    float acc[8] = {0.f, 0.f, 0.f, 0.f, 0.f, 0.f, 0.f, 0.f};
    int beg = row_off[n];
    int end = beg + indeg[n];
    int e = beg + q;
    while (e < end) {
        int eA = e + 4, eB = e + 8, eC = e + 12;
        int2 c0 = csr[e];
        int2 c1 = csr[(eA < end) ? eA : e];
        int2 c2 = csr[(eB < end) ? eB : e];
        int2 c3 = csr[(eC < end) ? eC : e];
        float w0 = __int_as_float(c0.y);
        float w1 = (eA < end) ? __int_as_float(c1.y) : 0.f;
        float w2 = (eB < end) ? __int_as_float(c2.y) : 0.f;
        float w3 = (eC < end) ? __int_as_float(c3.y) : 0.f;
        uint4 r0 = hW4[c0.x * 16 + c];
        uint4 r1 = hW4[c1.x * 16 + c];
        uint4 r2 = hW4[c2.x * 16 + c];
        uint4 r3 = hW4[c3.x * 16 + c];
        fma8(acc, r0, w0);
        fma8(acc, r1, w1);
        fma8(acc, r2, w2);
        fma8(acc, r3, w3);
        e += 16;
    }
#pragma unroll
    for (int i = 0; i < 8; ++i) {
        acc[i] += __shfl_xor(acc[i], 16, 64);
        acc[i] += __shfl_xor(acc[i], 32, 64);
    }
    if (q == 0) {
        float di = dinv[n];
        float sw = di * di;
        uint4 hv = hW4[n * 16 + c];
        fma8(acc, hv, sw);
        float4 bA = ((const float4*)bias)[c * 2];
        float4 bB = ((const float4*)bias)[c * 2 + 1];
        uint4 pk;
        pk.x = bf16pair(acc[0] + bA.x, acc[1] + bA.y);
        pk.y = bf16pair(acc[2] + bA.z, acc[3] + bA.w);
        pk.z = bf16pair(acc[4] + bB.x, acc[5] + bB.y);
        pk.w = bf16pair(acc[6] + bB.z, acc[7] + bB.w);
        outb[(size_t)n * 16 + c] = pk;
    }
}

// 32-dim agg on bf16 G -> p fp32 (no bias; bc folded into tail). Same 4-slot scheme.
__global__ __launch_bounds__(256) void agg32_kernel(const unsigned* __restrict__ Gb,
                                                    const float* __restrict__ dinv,
                                                    const int* __restrict__ row_off,
                                                    const int* __restrict__ indeg,
                                                    const int2* __restrict__ csr,
                                                    float* __restrict__ p) {
    int wave = threadIdx.x >> 6;
    int lane = threadIdx.x & 63;
    int n = blockIdx.x * 4 + wave;
    int q = lane >> 4;
    int c = lane & 15;
    const unsigned hm = 0xffff0000u;

    float a0 = 0.f, a1 = 0.f;
    int beg = row_off[n];
    int end = beg + indeg[n];
    int e = beg + q;
    while (e < end) {
        int eA = e + 4, eB = e + 8, eC = e + 12;
        int2 c0 = csr[e];
        int2 c1 = csr[(eA < end) ? eA : e];
        int2 c2 = csr[(eB < end) ? eB : e];
        int2 c3 = csr[(eC < end) ? eC : e];
        float w0 = __int_as_float(c0.y);
        float w1 = (eA < end) ? __int_as_float(c1.y) : 0.f;
        float w2 = (eB < end) ? __int_as_float(c2.y) : 0.f;
        float w3 = (eC < end) ? __int_as_float(c3.y) : 0.f;
        unsigned r0 = Gb[c0.x * 16 + c];
        unsigned r1 = Gb[c1.x * 16 + c];
        unsigned r2 = Gb[c2.x * 16 + c];
        unsigned r3 = Gb[c3.x * 16 + c];
        a0 += w0 * __uint_as_float(r0 << 16) + w1 * __uint_as_float(r1 << 16) +
              w2 * __uint_as_float(r2 << 16) + w3 * __uint_as_float(r3 << 16);
        a1 += w0 * __uint_as_float(r0 & hm) + w1 * __uint_as_float(r1 & hm) +
              w2 * __uint_as_float(r2 & hm) + w3 * __uint_as_float(r3 & hm);
        e += 16;
    }
    a0 += __shfl_xor(a0, 16, 64); a0 += __shfl_xor(a0, 32, 64);
    a1 += __shfl_xor(a1, 16, 64); a1 += __shfl_xor(a1, 32, 64);
    if (q == 0) {
        float di = dinv[n];
        float sw = di * di;
        unsigned sv = Gb[n * 16 + c];
        a0 += sw * __uint_as_float(sv << 16);
        a1 += sw * __uint_as_float(sv & hm);
        ((float2*)p)[n * 16 + c] = make_float2(a0, a1);
    }
}

// ---------------- tail ----------------

__global__ __launch_bounds__(256) void tail_kernel(const float* __restrict__ p,
                                                   const int* __restrict__ batch,
                                                   const float* __restrict__ bc,
                                                   float* __restrict__ out) {
    __shared__ float partial[8][32];
    int g = blockIdx.x;
    int t = threadIdx.x;
    int rg = t >> 5, d = t & 31;
    int lo = 0, hi = N_NODES;
    while (lo < hi) { int m = (lo + hi) >> 1; if (batch[m] < g) lo = m + 1; else hi = m; }
    int lo2 = lo, hi2 = N_NODES;
    while (lo2 < hi2) { int m = (lo2 + hi2) >> 1; if (batch[m] < g + 1) lo2 = m + 1; else hi2 = m; }
    int cnt = lo2 - lo;
    float acc = 0.f;
    int n = lo + rg;
    for (; n + 24 < lo2; n += 32) {
        float u0 = p[n * 32 + d];
        float u1 = p[(n + 8) * 32 + d];
        float u2 = p[(n + 16) * 32 + d];
        float u3 = p[(n + 24) * 32 + d];
        acc += (u0 + u1) + (u2 + u3);
    }
    for (; n < lo2; n += 8) acc += p[n * 32 + d];
    partial[rg][d] = acc;
    __syncthreads();
    if (rg == 0) {
        float s = 0.f;
#pragma unroll
        for (int r = 0; r < 8; ++r) s += partial[r][d];
        out[g * 32 + d] = (cnt > 0) ? s / (float)cnt + bc[d] : 0.f;
    }
}

// ---------------- launch ----------------

static inline size_t align_up(size_t x) { return (x + 255) & ~(size_t)255; }

extern "C" void kernel_launch(void* const* d_in, const int* in_sizes, int n_in,
                              void* d_out, int out_size, void* d_ws, size_t ws_size,
                              hipStream_t stream) {
    const float* x = (const float*)d_in[0];
    const int* edge_index = (const int*)d_in[1];
    const int* batch = (const int*)d_in[2];
    const float* W1 = (const float*)d_in[3];
    const float* b1 = (const float*)d_in[4];
    const float* W2 = (const float*)d_in[5];
    const float* b2 = (const float*)d_in[6];
    const float* W3 = (const float*)d_in[7];
    const float* b3 = (const float*)d_in[8];
    const float* W4 = (const float*)d_in[9];
    const float* b4 = (const float*)d_in[10];
    const float* fcW = (const float*)d_in[11];
    const float* fcb = (const float*)d_in[12];
    float* out = (float*)d_out;

    const int* src = edge_index;
    const int* dst = edge_index + N_EDGES;

    char* base = (char*)d_ws;
    size_t o = 0;
    unsigned* buf0 = (unsigned*)(base + o); o = align_up(o + (size_t)N_NODES * D * 2);
    unsigned* buf1 = (unsigned*)(base + o); o = align_up(o + (size_t)N_NODES * D * 2);
    int2* csr = (int2*)(base + o);          o = align_up(o + (size_t)N_EDGES * 8);
    int* row_off = (int*)(base + o);        o = align_up(o + (size_t)N_NODES * 4);
    int* indeg = (int*)(base + o);          o = align_up(o + (size_t)N_NODES * 4);
    int* cursor = (int*)(base + o);         o = align_up(o + (size_t)N_NODES * 4);
    float* dinv = (float*)(base + o);       o = align_up(o + (size_t)N_NODES * 4);
    int* bsum = (int*)(base + o);           o = align_up(o + 256);
    unsigned* WT1 = (unsigned*)(base + o);  o = align_up(o + (size_t)D * D * 2);
    unsigned* WT2 = (unsigned*)(base + o);  o = align_up(o + (size_t)D * D * 2);
    unsigned* WT3 = (unsigned*)(base + o);  o = align_up(o + (size_t)D * D * 2);
    unsigned short* WcT = (unsigned short*)(base + o); o = align_up(o + (size_t)D * D_OUT * 2);
    float* bc = (float*)(base + o);         o = align_up(o + (size_t)D_OUT * 4);
    float* p = (float*)(base + o);          o = align_up(o + (size_t)N_NODES * D_OUT * 4);

    hipMemsetAsync(indeg, 0, (size_t)N_NODES * 4, stream);
    hist_kernel<<<(N_EDGES + 255) / 256, 256, 0, stream>>>(dst, indeg);
    scanC_prep_kernel<<<N_SCAN_BLOCKS + 20, 256, 0, stream>>>(
        indeg, bsum, W1, W2, W3, W4, fcW, fcb, b4, WT1, WT2, WT3, WcT, bc);
    scanD_kernel<<<N_SCAN_BLOCKS, 256, 0, stream>>>(indeg, bsum, row_off, dinv, cursor);
    fill_kernel<<<(N_EDGES + 255) / 256, 256, 0, stream>>>(src, dst, row_off, cursor,
                                                           dinv, csr);

    gemm1_kernel<<<GEMM_BLOCKS, 256, 0, stream>>>(x, (const unsigned short*)WT1,
                                                  (uint4*)buf0);
    agg_kernel<<<AGG_GRID, 256, 0, stream>>>(buf0, b1, dinv, row_off, indeg, csr,
                                             (uint4*)buf1);
    gemm_kernel<<<GEMM_BLOCKS, 256, 0, stream>>>((const unsigned short*)buf1,
                                                 (const unsigned short*)WT2, (uint4*)buf0);
    agg_kernel<<<AGG_GRID, 256, 0, stream>>>(buf0, b2, dinv, row_off, indeg, csr,
                                             (uint4*)buf1);
    gemm_kernel<<<GEMM_BLOCKS, 256, 0, stream>>>((const unsigned short*)buf1,
                                                 (const unsigned short*)WT3, (uint4*)buf0);
    agg_kernel<<<AGG_GRID, 256, 0, stream>>>(buf0, b3, dinv, row_off, indeg, csr,
                                             (uint4*)buf1);
    gemm32_kernel<<<GEMM_BLOCKS, 256, 0, stream>>>((const unsigned short*)buf1, WcT,
                                                   (uint4*)buf0);  // Gb = buf0
    agg32_kernel<<<AGG_GRID, 256, 0, stream>>>(buf0, dinv, row_off, indeg, csr, p);
    tail_kernel<<<N_GRAPHS, 256, 0, stream>>>(p, batch, bc, out);
}